// Round 1
// baseline (4507.274 us; speedup 1.0000x reference)
//
#include <hip/hip_runtime.h>
#include <math.h>

// ---------------- dims ----------------
// T=S=48, H=250, EMB=300, gates=1000, 13 sim planes, convnet 48->24->12->6->3->1

// workspace layout (floats)
#define OFF_XW    0           // 4 * 48 * 1000 = 192000
#define OFF_HS    192000      // 4 * 48 * 250  = 48000
#define OFF_NORM  240000      // 2 * 48 * 3    = 288
#define OFF_SC    240288      // 13 * 2304     = 29952
#define OFF_MASK  270240      // 2304
#define OFF_BUF0  272544      // max 29952  (conv in / conv2 out / conv4 out)
#define OFF_BUF1  302496      // max 73728  (conv1 out / conv3 out / conv5 out)

__device__ __forceinline__ float sigf(float x) { return 1.f / (1.f + expf(-x)); }

// ---------------- 1) embedding gather + x @ w_ih^T ----------------
// grid: 192 blocks = (m in 0..3) * 48 t ; block 256
// m: 0 = seq1 fwd, 1 = seq1 bwd, 2 = seq2 fwd, 3 = seq2 bwd
__global__ void embed_xw_kernel(const int* __restrict__ x1, const int* __restrict__ x2,
                                const float* __restrict__ emb,
                                const float* __restrict__ w_ih_f, const float* __restrict__ w_ih_b,
                                float* __restrict__ xW)
{
    int t = blockIdx.x % 48;
    int m = blockIdx.x / 48;
    const int* x = (m < 2) ? x1 : x2;
    const float* w = (m & 1) ? w_ih_b : w_ih_f;

    __shared__ float e[300];
    int row = x[t];
    for (int k = threadIdx.x; k < 300; k += blockDim.x)
        e[k] = emb[(size_t)row * 300 + k];
    __syncthreads();

    float* out = xW + ((size_t)m * 48 + t) * 1000;
    for (int j = threadIdx.x; j < 1000; j += blockDim.x) {
        const float* wr = w + (size_t)j * 300;
        float acc = 0.f;
        #pragma unroll 4
        for (int k = 0; k < 300; ++k) acc += e[k] * wr[k];
        out[j] = acc;
    }
}

// ---------------- 2) LSTM recurrence: one block per direction ----------------
__global__ void __launch_bounds__(1024) lstm_kernel(
    const float* __restrict__ xW,
    const float* __restrict__ w_hh_f, const float* __restrict__ b_f,
    const float* __restrict__ w_hh_b, const float* __restrict__ b_b,
    float* __restrict__ hs)
{
    int m = blockIdx.x;           // 0..3
    bool rev = (m & 1);
    const float* w_hh = rev ? w_hh_b : w_hh_f;
    const float* bias = rev ? b_b : b_f;
    const float* xw = xW + (size_t)m * 48 * 1000;
    float* out = hs + (size_t)m * 48 * 250;

    __shared__ float h[250];
    __shared__ float c[250];
    __shared__ float g[1000];

    int j = threadIdx.x;
    if (j < 250) { h[j] = 0.f; c[j] = 0.f; }
    __syncthreads();

    for (int step = 0; step < 48; ++step) {
        int t = rev ? 47 - step : step;
        if (j < 1000) {
            const float* wr = w_hh + (size_t)j * 250;
            float acc = xw[t * 1000 + j] + bias[j];
            #pragma unroll 5
            for (int k = 0; k < 250; ++k) acc += h[k] * wr[k];
            g[j] = acc;
        }
        __syncthreads();
        if (j < 250) {
            float iv = sigf(g[j]);
            float fv = sigf(g[250 + j]);
            float gv = tanhf(g[500 + j]);
            float ov = sigf(g[750 + j]);
            float cn = fv * c[j] + iv * gv;
            c[j] = cn;
            float hn = ov * tanhf(cn);
            h[j] = hn;
            out[t * 250 + j] = hn;
        }
        __syncthreads();
    }
}

// ---------------- 3) per-row norms: nf, nb, nsum ----------------
// grid 96 = (seq in 0..1)*48 rows ; block 64
__global__ void norm_kernel(const float* __restrict__ hs, float* __restrict__ norms)
{
    int b = blockIdx.x;
    int seq = b / 48, row = b % 48;
    const float* hf = hs + ((size_t)(seq * 2 + 0) * 48 + row) * 250;
    const float* hb = hs + ((size_t)(seq * 2 + 1) * 48 + row) * 250;
    int lane = threadIdx.x;
    float sf = 0.f, sb = 0.f, ss = 0.f;
    for (int k = lane; k < 250; k += 64) {
        float a = hf[k], bb = hb[k];
        sf += a * a; sb += bb * bb;
        float s = a + bb; ss += s * s;
    }
    for (int o = 32; o; o >>= 1) {
        sf += __shfl_down(sf, o);
        sb += __shfl_down(sb, o);
        ss += __shfl_down(ss, o);
    }
    if (lane == 0) {
        float* p = norms + b * 3;
        p[0] = sf; p[1] = sb; p[2] = ss;
    }
}

// ---------------- 4) similarity cube: 13 x 48 x 48 ----------------
// grid 2304 blocks (one pair each), block 64
__global__ void sim_kernel(const float* __restrict__ hs, const float* __restrict__ norms,
                           float* __restrict__ sc)
{
    int p = blockIdx.x;           // pair index i*48 + j
    int i = p / 48, jj = p % 48;
    const float* h1f = hs + ((size_t)0 * 48 + i) * 250;
    const float* h1b = hs + ((size_t)1 * 48 + i) * 250;
    const float* h2f = hs + ((size_t)2 * 48 + jj) * 250;
    const float* h2b = hs + ((size_t)3 * 48 + jj) * 250;
    int lane = threadIdx.x;
    float dff = 0.f, dbb = 0.f, dfb = 0.f, dbf = 0.f;
    for (int k = lane; k < 250; k += 64) {
        float af = h1f[k], ab = h1b[k], bf = h2f[k], bb = h2b[k];
        dff += af * bf; dbb += ab * bb; dfb += af * bb; dbf += ab * bf;
    }
    for (int o = 32; o; o >>= 1) {
        dff += __shfl_down(dff, o);
        dbb += __shfl_down(dbb, o);
        dfb += __shfl_down(dfb, o);
        dbf += __shfl_down(dbf, o);
    }
    if (lane == 0) {
        float n1f = norms[(0 * 48 + i) * 3 + 0];
        float n1b = norms[(0 * 48 + i) * 3 + 1];
        float n1s = norms[(0 * 48 + i) * 3 + 2];
        float n2f = norms[(48 + jj) * 3 + 0];
        float n2b = norms[(48 + jj) * 3 + 1];
        float n2s = norms[(48 + jj) * 3 + 2];

        #define EMIT(base, dotv, sa, sb2)                                   \
        {                                                                   \
            float na = sqrtf(sa), nbv = sqrtf(sb2);                         \
            float dv = (dotv);                                              \
            sc[(base) * 2304 + p] = dv;                                     \
            sc[((base) + 1) * 2304 + p] = dv / (na * nbv + 1e-8f);          \
            float d2 = fmaxf(na * na + nbv * nbv - 2.f * dv, 1e-12f);       \
            sc[((base) + 2) * 2304 + p] = sqrtf(d2);                        \
        }
        EMIT(0, dff + dbb, n1f + n1b, n2f + n2b);
        EMIT(3, dff, n1f, n2f);
        EMIT(6, dbb, n1b, n2b);
        EMIT(9, dff + dfb + dbf + dbb, n1s, n2s);
        #undef EMIT
        sc[12 * 2304 + p] = 0.f;
    }
}

// ---------------- 5) greedy top-k focus mask ----------------
// one block, 256 threads. Replicates lax.top_k order (desc value, lower index
// first on ties) + sequential greedy bipartite marking; union over planes 10,11.
__global__ void greedy_mask_kernel(const float* __restrict__ sc, float* __restrict__ mask)
{
    __shared__ float vals[2304];
    __shared__ unsigned char sel[2304];
    __shared__ int s1[48], s2[48];
    __shared__ float bestV[256];
    __shared__ int bestI[256];

    int tid = threadIdx.x;
    for (int i = tid; i < 2304; i += 256) sel[i] = 0;

    for (int pl = 0; pl < 2; ++pl) {
        int plane = 10 + pl;
        for (int i = tid; i < 2304; i += 256) vals[i] = sc[plane * 2304 + i];
        if (tid < 48) { s1[tid] = 0; s2[tid] = 0; }
        __syncthreads();

        for (int it = 0; it < 96; ++it) {
            float bv = -INFINITY; int bi = 0x7fffffff;
            for (int i = tid; i < 2304; i += 256) {
                float v = vals[i];
                if (v > bv) { bv = v; bi = i; }   // within a thread i increases -> ties keep lower i
            }
            bestV[tid] = bv; bestI[tid] = bi;
            __syncthreads();
            for (int s = 128; s > 0; s >>= 1) {
                if (tid < s) {
                    float ov = bestV[tid + s]; int oi = bestI[tid + s];
                    if (ov > bestV[tid] || (ov == bestV[tid] && oi < bestI[tid])) {
                        bestV[tid] = ov; bestI[tid] = oi;
                    }
                }
                __syncthreads();
            }
            if (tid == 0) {
                int i = bestI[0];
                vals[i] = -INFINITY;
                int p1 = i / 48, p2 = i % 48;
                if (s1[p1] == 0 && s2[p2] == 0) {
                    s1[p1] = 1; s2[p2] = 1; sel[i] = 1;
                }
            }
            __syncthreads();
        }
    }
    for (int i = tid; i < 2304; i += 256) mask[i] = sel[i] ? 1.0f : 0.1f;
}

// ---------------- 6) apply focus mask -> conv input ----------------
__global__ void mask_kernel(const float* __restrict__ sc, const float* __restrict__ mask,
                            float* __restrict__ fc)
{
    int i = blockIdx.x * blockDim.x + threadIdx.x;
    if (i < 13 * 2304) fc[i] = sc[i] * mask[i % 2304];
}

// ---------------- 7) fused conv3x3(pad1) + bias + relu + maxpool ----------------
__global__ void conv_relu_pool_kernel(const float* __restrict__ in, const float* __restrict__ w,
                                      const float* __restrict__ bias, float* __restrict__ out,
                                      int Cin, int H, int W, int Cout,
                                      int poolK, int poolS, int PH, int PW)
{
    int idx = blockIdx.x * blockDim.x + threadIdx.x;
    int total = Cout * PH * PW;
    if (idx >= total) return;
    int px = idx % PW;
    int py = (idx / PW) % PH;
    int co = idx / (PW * PH);

    float best = -INFINITY;
    for (int dy = 0; dy < poolK; ++dy) {
        for (int dx = 0; dx < poolK; ++dx) {
            int y = py * poolS + dy;
            int x = px * poolS + dx;
            float acc = bias[co];
            for (int ci = 0; ci < Cin; ++ci) {
                const float* inp = in + (size_t)ci * H * W;
                const float* wp = w + (((size_t)co * Cin + ci) * 9);
                #pragma unroll
                for (int ky = 0; ky < 3; ++ky) {
                    int iy = y + ky - 1;
                    if (iy < 0 || iy >= H) continue;
                    #pragma unroll
                    for (int kx = 0; kx < 3; ++kx) {
                        int ix = x + kx - 1;
                        if (ix < 0 || ix >= W) continue;
                        acc += inp[iy * W + ix] * wp[ky * 3 + kx];
                    }
                }
            }
            float r = acc > 0.f ? acc : 0.f;
            best = r > best ? r : best;
        }
    }
    out[idx] = best;
}

// ---------------- 8) head: dnn + out + log_softmax ----------------
__global__ void head_kernel(const float* __restrict__ feat,
                            const float* __restrict__ dnn_w, const float* __restrict__ dnn_b,
                            const float* __restrict__ out_w, const float* __restrict__ out_b,
                            float* __restrict__ out)
{
    __shared__ float y[128];
    __shared__ float logits[5];
    int j = threadIdx.x;
    float acc = dnn_b[j];
    for (int k = 0; k < 128; ++k) acc += feat[k] * dnn_w[j * 128 + k];
    y[j] = acc > 0.f ? acc : 0.f;
    __syncthreads();
    if (j < 5) {
        float a = out_b[j];
        for (int k = 0; k < 128; ++k) a += y[k] * out_w[j * 128 + k];
        logits[j] = a;
    }
    __syncthreads();
    if (j == 0) {
        float m = logits[0];
        for (int l = 1; l < 5; ++l) m = fmaxf(m, logits[l]);
        float s = 0.f;
        for (int l = 0; l < 5; ++l) s += expf(logits[l] - m);
        float lse = logf(s);
        for (int l = 0; l < 5; ++l) out[l] = logits[l] - m - lse;
    }
}

extern "C" void kernel_launch(void* const* d_in, const int* in_sizes, int n_in,
                              void* d_out, int out_size, void* d_ws, size_t ws_size,
                              hipStream_t stream)
{
    const int*   x1     = (const int*)d_in[0];
    const int*   x2     = (const int*)d_in[1];
    const float* emb    = (const float*)d_in[2];
    const float* w_ih_f = (const float*)d_in[3];
    const float* w_hh_f = (const float*)d_in[4];
    const float* b_f    = (const float*)d_in[5];
    const float* w_ih_b = (const float*)d_in[6];
    const float* w_hh_b = (const float*)d_in[7];
    const float* b_b    = (const float*)d_in[8];
    const float* c1_w   = (const float*)d_in[9];
    const float* c1_b   = (const float*)d_in[10];
    const float* c2_w   = (const float*)d_in[11];
    const float* c2_b   = (const float*)d_in[12];
    const float* c3_w   = (const float*)d_in[13];
    const float* c3_b   = (const float*)d_in[14];
    const float* c4_w   = (const float*)d_in[15];
    const float* c4_b   = (const float*)d_in[16];
    const float* c5_w   = (const float*)d_in[17];
    const float* c5_b   = (const float*)d_in[18];
    const float* dnn_w  = (const float*)d_in[19];
    const float* dnn_b  = (const float*)d_in[20];
    const float* out_w  = (const float*)d_in[21];
    const float* out_b  = (const float*)d_in[22];

    float* ws   = (float*)d_ws;
    float* xW   = ws + OFF_XW;
    float* hs   = ws + OFF_HS;
    float* nrm  = ws + OFF_NORM;
    float* sc   = ws + OFF_SC;
    float* mask = ws + OFF_MASK;
    float* buf0 = ws + OFF_BUF0;
    float* buf1 = ws + OFF_BUF1;
    float* outp = (float*)d_out;

    embed_xw_kernel<<<192, 256, 0, stream>>>(x1, x2, emb, w_ih_f, w_ih_b, xW);
    lstm_kernel<<<4, 1024, 0, stream>>>(xW, w_hh_f, b_f, w_hh_b, b_b, hs);
    norm_kernel<<<96, 64, 0, stream>>>(hs, nrm);
    sim_kernel<<<2304, 64, 0, stream>>>(hs, nrm, sc);
    greedy_mask_kernel<<<1, 256, 0, stream>>>(sc, mask);
    mask_kernel<<<(13 * 2304 + 255) / 256, 256, 0, stream>>>(sc, mask, buf0);

    // conv stack: 13x48x48 ->128x24x24 ->164x12x12 ->192x6x6 ->192x3x3 ->128x1x1
    conv_relu_pool_kernel<<<(128 * 24 * 24 + 255) / 256, 256, 0, stream>>>(
        buf0, c1_w, c1_b, buf1, 13, 48, 48, 128, 2, 2, 24, 24);
    conv_relu_pool_kernel<<<(164 * 12 * 12 + 255) / 256, 256, 0, stream>>>(
        buf1, c2_w, c2_b, buf0, 128, 24, 24, 164, 2, 2, 12, 12);
    conv_relu_pool_kernel<<<(192 * 6 * 6 + 255) / 256, 256, 0, stream>>>(
        buf0, c3_w, c3_b, buf1, 164, 12, 12, 192, 2, 2, 6, 6);
    conv_relu_pool_kernel<<<(192 * 3 * 3 + 255) / 256, 256, 0, stream>>>(
        buf1, c4_w, c4_b, buf0, 192, 6, 6, 192, 2, 2, 3, 3);
    conv_relu_pool_kernel<<<1, 256, 0, stream>>>(
        buf0, c5_w, c5_b, buf1, 192, 3, 3, 128, 3, 1, 1, 1);

    head_kernel<<<1, 128, 0, stream>>>(buf1, dnn_w, dnn_b, out_w, out_b, outp);
}

// Round 2
// 1231.992 us; speedup vs baseline: 3.6585x; 3.6585x over previous
//
#include <hip/hip_runtime.h>
#include <math.h>

// ---------------- dims ----------------
// T=S=48, H=250, EMB=300, gates=1000, 13 sim planes, convnet 48->24->12->6->3->1

typedef __attribute__((ext_vector_type(8))) _Float16 h8;
typedef __attribute__((ext_vector_type(2))) _Float16 half2_t;

// workspace layout (floats)
#define OFF_XW    0            // 4*48*1000 = 192000
#define OFF_HS    192000       // 4*48*250  = 48000
#define OFF_NORM  240000       // 288
#define OFF_SC    240288       // 13*2304 = 29952
#define OFF_MASK  270240       // 2304
#define OFF_FC    272544       // 29952
#define OFF_BUFA  302496       // 294912 (max conv out 128x48x48)
#define OFF_BUFB  597408       // 73728  (max pooled 128x24x24)
#define OFF_WIHT  671136       // 2*300000 fp32 transposed w_ih [300][1000]
#define OFF_WHH8  1271136      // 2*124000 floats = 2 * 31*1000 h8 (fp16) packed w_hh
#define OFF_WHHT  1519136      // 2*500 floats = 2 * 1000 half2 tail (k=248,249)
// total ~1521136 floats (~6.1 MB)

__device__ __forceinline__ float sigf(float x) { return 1.f / (1.f + expf(-x)); }

// ---------------- 0a) transpose w_ih: [1000][300] -> [300][1000], fp32 ----------------
__global__ void transpose_wih_kernel(const float* __restrict__ wf, const float* __restrict__ wb,
                                     float* __restrict__ wT)
{
    int idx = blockIdx.x * blockDim.x + threadIdx.x;
    if (idx >= 600000) return;
    int dir = idx / 300000;
    int r = idx % 300000;
    int k = r / 1000, j = r % 1000;
    const float* w = dir ? wb : wf;
    wT[idx] = w[(size_t)j * 300 + k];
}

// ---------------- 0b) pack w_hh to fp16: [1000][250] -> h8[31][1000] + half2 tail[1000] ----------------
__global__ void pack_whh_kernel(const float* __restrict__ wf, const float* __restrict__ wb,
                                unsigned short* __restrict__ w8, unsigned short* __restrict__ wtail)
{
    int idx = blockIdx.x * blockDim.x + threadIdx.x;
    if (idx < 62000) {
        int dir = idx / 31000;
        int r = idx % 31000;
        int k8 = r / 1000, j = r % 1000;
        const float* w = dir ? wb : wf;
        h8 v;
        #pragma unroll
        for (int q = 0; q < 8; ++q) v[q] = (_Float16)w[(size_t)j * 250 + k8 * 8 + q];
        *(h8*)(w8 + (size_t)idx * 8) = v;   // idx == dir*31000 + k8*1000 + j
    } else if (idx < 64000) {
        int i2 = idx - 62000;
        int dir = i2 / 1000, j = i2 % 1000;
        const float* w = dir ? wb : wf;
        half2_t v;
        v.x = (_Float16)w[(size_t)j * 250 + 248];
        v.y = (_Float16)w[(size_t)j * 250 + 249];
        *(half2_t*)(wtail + (size_t)i2 * 2) = v;
    }
}

// ---------------- 1) embedding gather + x @ w_ih^T (coalesced via wT) ----------------
// grid: 192 = (m 0..3) * 48 t ; block 512
__global__ void embed_xw_kernel(const int* __restrict__ x1, const int* __restrict__ x2,
                                const float* __restrict__ emb, const float* __restrict__ wT,
                                float* __restrict__ xW)
{
    int t = blockIdx.x % 48;
    int m = blockIdx.x / 48;
    const int* x = (m < 2) ? x1 : x2;
    const float* w = wT + (size_t)(m & 1) * 300000;

    __shared__ float e[300];
    int row = x[t];
    for (int k = threadIdx.x; k < 300; k += 512)
        e[k] = emb[(size_t)row * 300 + k];
    __syncthreads();

    int j0 = threadIdx.x;
    int j1 = threadIdx.x + 512;
    int j1c = j1 < 1000 ? j1 : 999;
    float a0 = 0.f, a1 = 0.f;
    #pragma unroll 4
    for (int k = 0; k < 300; ++k) {
        float ek = e[k];
        const float* wr = w + (size_t)k * 1000;
        a0 += ek * wr[j0];
        a1 += ek * wr[j1c];
    }
    float* out = xW + ((size_t)m * 48 + t) * 1000;
    out[j0] = a0;
    if (j1 < 1000) out[j1] = a1;
}

// ---------------- 2) LSTM recurrence: one block per (seq,dir); fp16 packed weights ----------------
__global__ void __launch_bounds__(1024) lstm_kernel(
    const float* __restrict__ xW,
    const unsigned short* __restrict__ w8, const unsigned short* __restrict__ wtail,
    const float* __restrict__ b_f, const float* __restrict__ b_b,
    float* __restrict__ hs)
{
    int m = blockIdx.x;           // 0: s1 fwd, 1: s1 bwd, 2: s2 fwd, 3: s2 bwd
    int dir = m & 1;
    const h8* wp = (const h8*)(w8 + (size_t)dir * 31000 * 8);
    const half2_t* wt = (const half2_t*)(wtail + (size_t)dir * 2000);
    const float* bias = dir ? b_b : b_f;
    const float* xw = xW + (size_t)m * 48 * 1000;
    float* out = hs + (size_t)m * 48 * 250;

    __shared__ float h[256];      // padded for float4 reads
    __shared__ float g[1000];

    int j = threadIdx.x;
    if (j < 256) h[j] = 0.f;
    float c = 0.f;
    float bias_j = (j < 1000) ? bias[j] : 0.f;
    __syncthreads();

    for (int step = 0; step < 48; ++step) {
        int t = dir ? 47 - step : step;
        if (j < 1000) {
            float acc = xw[t * 1000 + j] + bias_j;
            #pragma unroll 4
            for (int k8 = 0; k8 < 31; ++k8) {
                h8 wv = wp[k8 * 1000 + j];
                float4 hv0 = *(const float4*)&h[k8 * 8];
                float4 hv1 = *(const float4*)&h[k8 * 8 + 4];
                acc += (float)wv[0] * hv0.x + (float)wv[1] * hv0.y +
                       (float)wv[2] * hv0.z + (float)wv[3] * hv0.w +
                       (float)wv[4] * hv1.x + (float)wv[5] * hv1.y +
                       (float)wv[6] * hv1.z + (float)wv[7] * hv1.w;
            }
            half2_t tw = wt[j];
            acc += (float)tw.x * h[248] + (float)tw.y * h[249];
            g[j] = acc;
        }
        __syncthreads();
        if (j < 250) {
            float iv = sigf(g[j]);
            float fv = sigf(g[250 + j]);
            float gv = tanhf(g[500 + j]);
            float ov = sigf(g[750 + j]);
            c = fv * c + iv * gv;
            float hn = ov * tanhf(c);
            h[j] = hn;
            out[t * 250 + j] = hn;
        }
        __syncthreads();
    }
}

// ---------------- 3) per-row norms ----------------
__global__ void norm_kernel(const float* __restrict__ hs, float* __restrict__ norms)
{
    int b = blockIdx.x;
    int seq = b / 48, row = b % 48;
    const float* hf = hs + ((size_t)(seq * 2 + 0) * 48 + row) * 250;
    const float* hb = hs + ((size_t)(seq * 2 + 1) * 48 + row) * 250;
    int lane = threadIdx.x;
    float sf = 0.f, sb = 0.f, ss = 0.f;
    for (int k = lane; k < 250; k += 64) {
        float a = hf[k], bb = hb[k];
        sf += a * a; sb += bb * bb;
        float s = a + bb; ss += s * s;
    }
    for (int o = 32; o; o >>= 1) {
        sf += __shfl_down(sf, o);
        sb += __shfl_down(sb, o);
        ss += __shfl_down(ss, o);
    }
    if (lane == 0) {
        float* p = norms + b * 3;
        p[0] = sf; p[1] = sb; p[2] = ss;
    }
}

// ---------------- 4) similarity cube: 13 x 48 x 48 ----------------
__global__ void sim_kernel(const float* __restrict__ hs, const float* __restrict__ norms,
                           float* __restrict__ sc)
{
    int p = blockIdx.x;
    int i = p / 48, jj = p % 48;
    const float* h1f = hs + ((size_t)0 * 48 + i) * 250;
    const float* h1b = hs + ((size_t)1 * 48 + i) * 250;
    const float* h2f = hs + ((size_t)2 * 48 + jj) * 250;
    const float* h2b = hs + ((size_t)3 * 48 + jj) * 250;
    int lane = threadIdx.x;
    float dff = 0.f, dbb = 0.f, dfb = 0.f, dbf = 0.f;
    for (int k = lane; k < 250; k += 64) {
        float af = h1f[k], ab = h1b[k], bf = h2f[k], bb = h2b[k];
        dff += af * bf; dbb += ab * bb; dfb += af * bb; dbf += ab * bf;
    }
    for (int o = 32; o; o >>= 1) {
        dff += __shfl_down(dff, o);
        dbb += __shfl_down(dbb, o);
        dfb += __shfl_down(dfb, o);
        dbf += __shfl_down(dbf, o);
    }
    if (lane == 0) {
        float n1f = norms[(0 * 48 + i) * 3 + 0];
        float n1b = norms[(0 * 48 + i) * 3 + 1];
        float n1s = norms[(0 * 48 + i) * 3 + 2];
        float n2f = norms[(48 + jj) * 3 + 0];
        float n2b = norms[(48 + jj) * 3 + 1];
        float n2s = norms[(48 + jj) * 3 + 2];

        #define EMIT(base, dotv, sa, sb2)                                   \
        {                                                                   \
            float na = sqrtf(sa), nbv = sqrtf(sb2);                         \
            float dv = (dotv);                                              \
            sc[(base) * 2304 + p] = dv;                                     \
            sc[((base) + 1) * 2304 + p] = dv / (na * nbv + 1e-8f);          \
            float d2 = fmaxf(na * na + nbv * nbv - 2.f * dv, 1e-12f);       \
            sc[((base) + 2) * 2304 + p] = sqrtf(d2);                        \
        }
        EMIT(0, dff + dbb, n1f + n1b, n2f + n2b);
        EMIT(3, dff, n1f, n2f);
        EMIT(6, dbb, n1b, n2b);
        EMIT(9, dff + dfb + dbf + dbb, n1s, n2s);
        #undef EMIT
        sc[12 * 2304 + p] = 0.f;
    }
}

// ---------------- 5) greedy top-k focus mask: single wave, shuffle argmax ----------------
__global__ void greedy_mask_kernel(const float* __restrict__ sc, float* __restrict__ mask)
{
    __shared__ float vals[2304];
    __shared__ unsigned char sel[2304];
    __shared__ int s1[48], s2[48];
    int lane = threadIdx.x;

    for (int i = lane; i < 2304; i += 64) sel[i] = 0;

    for (int pl = 0; pl < 2; ++pl) {
        for (int i = lane; i < 2304; i += 64) vals[i] = sc[(10 + pl) * 2304 + i];
        if (lane < 48) { s1[lane] = 0; s2[lane] = 0; }
        __syncthreads();

        for (int it = 0; it < 96; ++it) {
            float bv = -INFINITY; int bi = 0x7fffffff;
            for (int i = lane; i < 2304; i += 64) {
                float v = vals[i];
                if (v > bv) { bv = v; bi = i; }    // ascending i -> ties keep lowest i
            }
            for (int o = 32; o; o >>= 1) {
                float ov = __shfl_down(bv, o);
                int   oi = __shfl_down(bi, o);
                if (ov > bv || (ov == bv && oi < bi)) { bv = ov; bi = oi; }
            }
            if (lane == 0) {
                vals[bi] = -INFINITY;
                int p1 = bi / 48, p2 = bi % 48;
                if (s1[p1] == 0 && s2[p2] == 0) {
                    s1[p1] = 1; s2[p2] = 1; sel[bi] = 1;
                }
            }
            __syncthreads();
        }
        __syncthreads();
    }
    for (int i = lane; i < 2304; i += 64) mask[i] = sel[i] ? 1.0f : 0.1f;
}

// ---------------- 6) apply focus mask ----------------
__global__ void mask_kernel(const float* __restrict__ sc, const float* __restrict__ mask,
                            float* __restrict__ fc)
{
    int i = blockIdx.x * blockDim.x + threadIdx.x;
    if (i < 13 * 2304) fc[i] = sc[i] * mask[i % 2304];
}

// ---------------- 7a) conv3x3(pad1) + bias + relu (no pool recompute) ----------------
__global__ void conv3x3_relu_kernel(const float* __restrict__ in, const float* __restrict__ w,
                                    const float* __restrict__ bias, float* __restrict__ out,
                                    int Cin, int H, int W, int Cout)
{
    int idx = blockIdx.x * blockDim.x + threadIdx.x;
    int total = Cout * H * W;
    if (idx >= total) return;
    int x = idx % W;
    int y = (idx / W) % H;
    int co = idx / (W * H);

    float acc = bias[co];
    const float* wco = w + (size_t)co * Cin * 9;
    for (int ci = 0; ci < Cin; ++ci) {
        const float* inp = in + (size_t)ci * H * W;
        const float* wp = wco + ci * 9;
        #pragma unroll
        for (int ky = 0; ky < 3; ++ky) {
            int iy = y + ky - 1;
            if (iy < 0 || iy >= H) continue;
            #pragma unroll
            for (int kx = 0; kx < 3; ++kx) {
                int ix = x + kx - 1;
                if (ix < 0 || ix >= W) continue;
                acc += inp[iy * W + ix] * wp[ky * 3 + kx];
            }
        }
    }
    out[idx] = acc > 0.f ? acc : 0.f;
}

// ---------------- 7b) maxpool ----------------
__global__ void maxpool_kernel(const float* __restrict__ in, float* __restrict__ out,
                               int C, int H, int W, int k, int st, int PH, int PW)
{
    int idx = blockIdx.x * blockDim.x + threadIdx.x;
    int total = C * PH * PW;
    if (idx >= total) return;
    int px = idx % PW;
    int py = (idx / PW) % PH;
    int cc = idx / (PW * PH);
    const float* inp = in + (size_t)cc * H * W;
    float best = -INFINITY;
    for (int dy = 0; dy < k; ++dy)
        for (int dx = 0; dx < k; ++dx) {
            float v = inp[(py * st + dy) * W + (px * st + dx)];
            best = v > best ? v : best;
        }
    out[idx] = best;
}

// ---------------- 8) head ----------------
__global__ void head_kernel(const float* __restrict__ feat,
                            const float* __restrict__ dnn_w, const float* __restrict__ dnn_b,
                            const float* __restrict__ out_w, const float* __restrict__ out_b,
                            float* __restrict__ out)
{
    __shared__ float y[128];
    __shared__ float logits[5];
    int j = threadIdx.x;
    float acc = dnn_b[j];
    for (int k = 0; k < 128; ++k) acc += feat[k] * dnn_w[j * 128 + k];
    y[j] = acc > 0.f ? acc : 0.f;
    __syncthreads();
    if (j < 5) {
        float a = out_b[j];
        for (int k = 0; k < 128; ++k) a += y[k] * out_w[j * 128 + k];
        logits[j] = a;
    }
    __syncthreads();
    if (j == 0) {
        float m = logits[0];
        for (int l = 1; l < 5; ++l) m = fmaxf(m, logits[l]);
        float s = 0.f;
        for (int l = 0; l < 5; ++l) s += expf(logits[l] - m);
        float lse = logf(s);
        for (int l = 0; l < 5; ++l) out[l] = logits[l] - m - lse;
    }
}

extern "C" void kernel_launch(void* const* d_in, const int* in_sizes, int n_in,
                              void* d_out, int out_size, void* d_ws, size_t ws_size,
                              hipStream_t stream)
{
    const int*   x1     = (const int*)d_in[0];
    const int*   x2     = (const int*)d_in[1];
    const float* emb    = (const float*)d_in[2];
    const float* w_ih_f = (const float*)d_in[3];
    const float* w_hh_f = (const float*)d_in[4];
    const float* b_f    = (const float*)d_in[5];
    const float* w_ih_b = (const float*)d_in[6];
    const float* w_hh_b = (const float*)d_in[7];
    const float* b_b    = (const float*)d_in[8];
    const float* c1_w   = (const float*)d_in[9];
    const float* c1_b   = (const float*)d_in[10];
    const float* c2_w   = (const float*)d_in[11];
    const float* c2_b   = (const float*)d_in[12];
    const float* c3_w   = (const float*)d_in[13];
    const float* c3_b   = (const float*)d_in[14];
    const float* c4_w   = (const float*)d_in[15];
    const float* c4_b   = (const float*)d_in[16];
    const float* c5_w   = (const float*)d_in[17];
    const float* c5_b   = (const float*)d_in[18];
    const float* dnn_w  = (const float*)d_in[19];
    const float* dnn_b  = (const float*)d_in[20];
    const float* out_w  = (const float*)d_in[21];
    const float* out_b  = (const float*)d_in[22];

    float* ws    = (float*)d_ws;
    float* xW    = ws + OFF_XW;
    float* hsb   = ws + OFF_HS;
    float* nrm   = ws + OFF_NORM;
    float* sc    = ws + OFF_SC;
    float* mask  = ws + OFF_MASK;
    float* fc    = ws + OFF_FC;
    float* bufA  = ws + OFF_BUFA;
    float* bufB  = ws + OFF_BUFB;
    float* wihT  = ws + OFF_WIHT;
    unsigned short* whh8 = (unsigned short*)(ws + OFF_WHH8);
    unsigned short* whht = (unsigned short*)(ws + OFF_WHHT);
    float* outp  = (float*)d_out;

    // weight prep
    transpose_wih_kernel<<<(600000 + 255) / 256, 256, 0, stream>>>(w_ih_f, w_ih_b, wihT);
    pack_whh_kernel<<<(64000 + 255) / 256, 256, 0, stream>>>(w_hh_f, w_hh_b, whh8, whht);

    embed_xw_kernel<<<192, 512, 0, stream>>>(x1, x2, emb, wihT, xW);
    lstm_kernel<<<4, 1024, 0, stream>>>(xW, whh8, whht, b_f, b_b, hsb);
    norm_kernel<<<96, 64, 0, stream>>>(hsb, nrm);
    sim_kernel<<<2304, 64, 0, stream>>>(hsb, nrm, sc);
    greedy_mask_kernel<<<1, 64, 0, stream>>>(sc, mask);
    mask_kernel<<<(13 * 2304 + 255) / 256, 256, 0, stream>>>(sc, mask, fc);

    // conv stack: 13x48x48 ->128x24x24 ->164x12x12 ->192x6x6 ->192x3x3 ->128x1x1
    conv3x3_relu_kernel<<<(128 * 48 * 48 + 255) / 256, 256, 0, stream>>>(fc,   c1_w, c1_b, bufA, 13, 48, 48, 128);
    maxpool_kernel<<<(128 * 24 * 24 + 255) / 256, 256, 0, stream>>>(bufA, bufB, 128, 48, 48, 2, 2, 24, 24);
    conv3x3_relu_kernel<<<(164 * 24 * 24 + 255) / 256, 256, 0, stream>>>(bufB, c2_w, c2_b, bufA, 128, 24, 24, 164);
    maxpool_kernel<<<(164 * 12 * 12 + 255) / 256, 256, 0, stream>>>(bufA, bufB, 164, 24, 24, 2, 2, 12, 12);
    conv3x3_relu_kernel<<<(192 * 12 * 12 + 255) / 256, 256, 0, stream>>>(bufB, c3_w, c3_b, bufA, 164, 12, 12, 192);
    maxpool_kernel<<<(192 * 6 * 6 + 255) / 256, 256, 0, stream>>>(bufA, bufB, 192, 12, 12, 2, 2, 6, 6);
    conv3x3_relu_kernel<<<(192 * 6 * 6 + 255) / 256, 256, 0, stream>>>(bufB, c4_w, c4_b, bufA, 192, 6, 6, 192);
    maxpool_kernel<<<(192 * 3 * 3 + 255) / 256, 256, 0, stream>>>(bufA, bufB, 192, 6, 6, 2, 2, 3, 3);
    conv3x3_relu_kernel<<<(128 * 3 * 3 + 255) / 256, 256, 0, stream>>>(bufB, c5_w, c5_b, bufA, 192, 3, 3, 128);
    maxpool_kernel<<<1, 128, 0, stream>>>(bufA, bufB, 128, 3, 3, 3, 1, 1, 1);

    head_kernel<<<1, 128, 0, stream>>>(bufB, dnn_w, dnn_b, out_w, out_b, outp);
}

// Round 3
// 1046.844 us; speedup vs baseline: 4.3056x; 1.1769x over previous
//
#include <hip/hip_runtime.h>
#include <math.h>

// ---------------- dims ----------------
// T=S=48, H=250, EMB=300, gates=1000, 13 sim planes, convnet 48->24->12->6->3->1

typedef __attribute__((ext_vector_type(2))) _Float16 h2f;

// workspace layout (floats)
#define OFF_XW    0            // 4*48*1000 = 192000
#define OFF_HS    192000       // 4*48*250  = 48000
#define OFF_SC    240000       // 13*2304 = 29952
#define OFF_FC    269952       // 29952
#define OFF_BUFA  299904       // 73728 (conv1 pooled 128x24x24; conv3 out; conv5 out)
#define OFF_BUFB  373632       // 23616 (conv2 pooled 164x12x12; conv4 out)
#define OFF_WIHT  397248       // 600000 fp32 transposed w_ih [2][300][1000]
#define OFF_HGLOB 997248       // 4 dirs * 2 parity * 256
#define OFF_CNT   999296       // 4 ints
#define OFF_SEL   999300       // 2 planes * 2304 bytes = 1152 floats
// total ~1000452 floats (~4.0 MB)

__device__ __forceinline__ float sigf(float x) { return 1.f / (1.f + expf(-x)); }

// ---------------- 0) tiled transpose w_ih: [1000][300] -> [300][1000] (+ zero sync counters) ----------------
// grid dim3(32, 10, 2), block dim3(32, 32)
__global__ void transpose_wih_kernel(const float* __restrict__ wf, const float* __restrict__ wb,
                                     float* __restrict__ wT, int* __restrict__ cnt)
{
    if (blockIdx.x == 0 && blockIdx.y == 0 && blockIdx.z == 0 &&
        threadIdx.y == 0 && threadIdx.x < 4)
        __hip_atomic_store(&cnt[threadIdx.x], 0, __ATOMIC_RELAXED, __HIP_MEMORY_SCOPE_AGENT);

    __shared__ float tile[32][33];
    int dir = blockIdx.z;
    const float* w = dir ? wb : wf;

    int j = blockIdx.x * 32 + threadIdx.y;   // row of w (0..999)
    int k = blockIdx.y * 32 + threadIdx.x;   // col of w (0..299)
    if (j < 1000 && k < 300)
        tile[threadIdx.y][threadIdx.x] = w[(size_t)j * 300 + k];
    __syncthreads();

    int ko = blockIdx.y * 32 + threadIdx.y;  // row of wT (0..299)
    int jo = blockIdx.x * 32 + threadIdx.x;  // col of wT (0..999)
    if (ko < 300 && jo < 1000)
        wT[(size_t)dir * 300000 + (size_t)ko * 1000 + jo] = tile[threadIdx.x][threadIdx.y];
}

// ---------------- 1) embedding gather + x @ w_ih^T (coalesced via wT) ----------------
__global__ void embed_xw_kernel(const int* __restrict__ x1, const int* __restrict__ x2,
                                const float* __restrict__ emb, const float* __restrict__ wT,
                                float* __restrict__ xW)
{
    int t = blockIdx.x % 48;
    int m = blockIdx.x / 48;
    const int* x = (m < 2) ? x1 : x2;
    const float* w = wT + (size_t)(m & 1) * 300000;

    __shared__ float e[300];
    int row = x[t];
    for (int k = threadIdx.x; k < 300; k += 512)
        e[k] = emb[(size_t)row * 300 + k];
    __syncthreads();

    int j0 = threadIdx.x;
    int j1 = threadIdx.x + 512;
    int j1c = j1 < 1000 ? j1 : 999;
    float a0 = 0.f, a1 = 0.f;
    #pragma unroll 4
    for (int k = 0; k < 300; ++k) {
        float ek = e[k];
        const float* wr = w + (size_t)k * 1000;
        a0 += ek * wr[j0];
        a1 += ek * wr[j1c];
    }
    float* out = xW + ((size_t)m * 48 + t) * 1000;
    out[j0] = a0;
    if (j1 < 1000) out[j1] = a1;
}

// ---------------- 2) LSTM: 16 blocks = 4 (seq,dir) x 4 slices; weights register-resident ----------------
// Cross-block h exchange per step via agent-scope atomics + parity double buffer.
__global__ void __launch_bounds__(256) lstm_kernel(
    const float* __restrict__ xW,
    const float* __restrict__ w_hh_f, const float* __restrict__ w_hh_b,
    const float* __restrict__ b_f, const float* __restrict__ b_b,
    float* __restrict__ hs, float* __restrict__ hglob, int* __restrict__ cnt)
{
    int blk = blockIdx.x;
    int m   = blk >> 2;             // 0: s1 fwd, 1: s1 bwd, 2: s2 fwd, 3: s2 bwd
    int s   = blk & 3;              // slice
    int dir = m & 1;
    const float* w    = dir ? w_hh_b : w_hh_f;
    const float* bias = dir ? b_b : b_f;
    const float* xw   = xW + (size_t)m * 48000;
    float* out        = hs + (size_t)m * 12000;

    const int NU   = (s < 2) ? 63 : 62;
    const int base = (s < 2) ? s * 63 : 126 + (s - 2) * 62;
    const int ROWS = 4 * NU;

    int t = threadIdx.x;
    bool active = t < ROWS;
    int gate = active ? t / NU : 0;
    int u    = active ? t % NU : 0;
    int grow = gate * 250 + base + u;

    __shared__ __align__(16) float h_lds[256];
    __shared__ float g_lds[256];

    // weights -> registers as packed fp16 pairs
    unsigned int wreg[125];
    float bias_r = 0.f;
    if (active) {
        bias_r = bias[grow];
        const float* wr = w + (size_t)grow * 250;
        #pragma unroll
        for (int j = 0; j < 125; ++j) {
            float2 v = *(const float2*)(wr + 2 * j);
            h2f pv; pv.x = (_Float16)v.x; pv.y = (_Float16)v.y;
            wreg[j] = *(unsigned int*)&pv;
        }
    }
    h_lds[t] = 0.f;
    float c = 0.f;
    __syncthreads();

    for (int step = 0; step < 48; ++step) {
        int tt = dir ? 47 - step : step;
        if (active) {
            float acc = xw[tt * 1000 + grow] + bias_r;
            #pragma unroll
            for (int j = 0; j < 125; ++j) {
                float2 hv = *(const float2*)&h_lds[2 * j];
                h2f wv = *(h2f*)&wreg[j];
                acc += (float)wv.x * hv.x + (float)wv.y * hv.y;
            }
            g_lds[t] = acc;
        }
        __syncthreads();
        int par = step & 1;
        if (t < NU) {
            float iv = sigf(g_lds[t]);
            float fv = sigf(g_lds[NU + t]);
            float gv = tanhf(g_lds[2 * NU + t]);
            float ov = sigf(g_lds[3 * NU + t]);
            c = fv * c + iv * gv;
            float hn = ov * tanhf(c);
            out[tt * 250 + base + t] = hn;
            __hip_atomic_store(&hglob[(m * 2 + par) * 256 + base + t], hn,
                               __ATOMIC_RELAXED, __HIP_MEMORY_SCOPE_AGENT);
        }
        __syncthreads();   // drains vmem: all h stores complete before signal
        if (t == 0) {
            __hip_atomic_fetch_add(&cnt[m], 1, __ATOMIC_RELEASE, __HIP_MEMORY_SCOPE_AGENT);
            while (__hip_atomic_load(&cnt[m], __ATOMIC_ACQUIRE, __HIP_MEMORY_SCOPE_AGENT)
                   < 4 * (step + 1)) {}
        }
        __syncthreads();
        if (t < 250)
            h_lds[t] = __hip_atomic_load(&hglob[(m * 2 + par) * 256 + t],
                                         __ATOMIC_RELAXED, __HIP_MEMORY_SCOPE_AGENT);
        __syncthreads();
    }
}

// ---------------- 3) similarity cube with inline norms: 13 x 48 x 48 ----------------
__global__ void sim_kernel(const float* __restrict__ hs, float* __restrict__ sc)
{
    int p = blockIdx.x;
    int i = p / 48, jj = p % 48;
    const float* h1f = hs + ((size_t)0 * 48 + i) * 250;
    const float* h1b = hs + ((size_t)1 * 48 + i) * 250;
    const float* h2f = hs + ((size_t)2 * 48 + jj) * 250;
    const float* h2b = hs + ((size_t)3 * 48 + jj) * 250;
    int lane = threadIdx.x;
    float dff = 0.f, dbb = 0.f, dfb = 0.f, dbf = 0.f;
    float sfa = 0.f, sba = 0.f, caa = 0.f;
    float sfb = 0.f, sbb = 0.f, cbb = 0.f;
    for (int k = lane; k < 250; k += 64) {
        float af = h1f[k], ab = h1b[k], bf = h2f[k], bb = h2b[k];
        dff += af * bf; dbb += ab * bb; dfb += af * bb; dbf += ab * bf;
        sfa += af * af; sba += ab * ab; caa += af * ab;
        sfb += bf * bf; sbb += bb * bb; cbb += bf * bb;
    }
    #pragma unroll
    for (int o = 32; o; o >>= 1) {
        dff += __shfl_down(dff, o); dbb += __shfl_down(dbb, o);
        dfb += __shfl_down(dfb, o); dbf += __shfl_down(dbf, o);
        sfa += __shfl_down(sfa, o); sba += __shfl_down(sba, o);
        caa += __shfl_down(caa, o);
        sfb += __shfl_down(sfb, o); sbb += __shfl_down(sbb, o);
        cbb += __shfl_down(cbb, o);
    }
    if (lane == 0) {
        #define EMIT(basep, dotv, sa2, sb2)                                 \
        {                                                                   \
            float na = sqrtf(sa2), nbv = sqrtf(sb2);                        \
            float dv = (dotv);                                              \
            sc[(basep) * 2304 + p] = dv;                                    \
            sc[((basep) + 1) * 2304 + p] = dv / (na * nbv + 1e-8f);         \
            float d2 = fmaxf(na * na + nbv * nbv - 2.f * dv, 1e-12f);       \
            sc[((basep) + 2) * 2304 + p] = sqrtf(d2);                       \
        }
        EMIT(0, dff + dbb, sfa + sba, sfb + sbb);
        EMIT(3, dff, sfa, sfb);
        EMIT(6, dbb, sba, sbb);
        EMIT(9, dff + dfb + dbf + dbb, sfa + sba + 2.f * caa, sfb + sbb + 2.f * cbb);
        #undef EMIT
        sc[12 * 2304 + p] = 0.f;
    }
}

// ---------------- 4) greedy top-k: 2 blocks (one per plane), single wave each ----------------
__global__ void greedy_kernel(const float* __restrict__ sc, unsigned char* __restrict__ sel)
{
    __shared__ float vals[2304];
    __shared__ int s1[48], s2[48];
    __shared__ unsigned char selL[2304];
    int lane = threadIdx.x;
    int plane = 10 + blockIdx.x;

    for (int q = 0; q < 36; ++q) {
        int i = lane + 64 * q;
        vals[i] = sc[plane * 2304 + i];
        selL[i] = 0;
    }
    if (lane < 48) { s1[lane] = 0; s2[lane] = 0; }
    __syncthreads();

    // per-lane cached local argmax over its 36 strided elements
    float lv = -INFINITY; int li = 0x7fffffff;
    for (int q = 0; q < 36; ++q) {
        int i = lane + 64 * q;
        float v = vals[i];
        if (v > lv) { lv = v; li = i; }
    }

    for (int it = 0; it < 96; ++it) {
        float bv = lv; int bi = li;
        #pragma unroll
        for (int o = 1; o < 64; o <<= 1) {
            float ov = __shfl_xor(bv, o);
            int   oi = __shfl_xor(bi, o);
            if (ov > bv || (ov == bv && oi < bi)) { bv = ov; bi = oi; }
        }
        // pop: owner lane invalidates + rescans; lane 0 does greedy marking
        if (lane == (bi & 63)) {
            vals[bi] = -INFINITY;
            lv = -INFINITY; li = 0x7fffffff;
            for (int q = 0; q < 36; ++q) {
                int i = lane + 64 * q;
                float v = vals[i];
                if (v > lv) { lv = v; li = i; }
            }
        }
        if (lane == 0) {
            int p1 = bi / 48, p2 = bi % 48;
            if (s1[p1] + s2[p2] == 0) { s1[p1] = 1; s2[p2] = 1; selL[bi] = 1; }
        }
    }
    __syncthreads();
    for (int q = 0; q < 36; ++q) {
        int i = lane + 64 * q;
        sel[blockIdx.x * 2304 + i] = selL[i];
    }
}

// ---------------- 5) apply focus mask ----------------
__global__ void mask_kernel(const float* __restrict__ sc, const unsigned char* __restrict__ sel,
                            float* __restrict__ fc)
{
    int i = blockIdx.x * blockDim.x + threadIdx.x;
    if (i < 13 * 2304) {
        int p = i % 2304;
        float m = (sel[p] | sel[2304 + p]) ? 1.0f : 0.1f;
        fc[i] = sc[i] * m;
    }
}

// ---------------- 6) conv1 (13->128, 48x48) + relu + pool2x2 via LDS tile ----------------
// grid 128*9, block 256 (16x16 tile)
__global__ void conv1_pool_kernel(const float* __restrict__ in, const float* __restrict__ w,
                                  const float* __restrict__ bias, float* __restrict__ out)
{
    __shared__ float tile[256];
    int co   = blockIdx.x / 9;
    int tl   = blockIdx.x % 9;
    int ty0  = (tl / 3) * 16, tx0 = (tl % 3) * 16;
    int tx = threadIdx.x % 16, ty = threadIdx.x / 16;
    int x = tx0 + tx, y = ty0 + ty;

    float acc = bias[co];
    const float* wco = w + (size_t)co * 13 * 9;
    for (int ci = 0; ci < 13; ++ci) {
        const float* inp = in + (size_t)ci * 2304;
        const float* wp = wco + ci * 9;
        #pragma unroll
        for (int ky = 0; ky < 3; ++ky) {
            int iy = y + ky - 1;
            if (iy < 0 || iy >= 48) continue;
            #pragma unroll
            for (int kx = 0; kx < 3; ++kx) {
                int ix = x + kx - 1;
                if (ix < 0 || ix >= 48) continue;
                acc += inp[iy * 48 + ix] * wp[ky * 3 + kx];
            }
        }
    }
    tile[threadIdx.x] = acc > 0.f ? acc : 0.f;
    __syncthreads();
    if (threadIdx.x < 64) {
        int py = threadIdx.x / 8, px = threadIdx.x % 8;
        float a = tile[(py * 2) * 16 + px * 2];
        float b = tile[(py * 2) * 16 + px * 2 + 1];
        float cc = tile[(py * 2 + 1) * 16 + px * 2];
        float d = tile[(py * 2 + 1) * 16 + px * 2 + 1];
        float best = fmaxf(fmaxf(a, b), fmaxf(cc, d));
        out[(size_t)co * 576 + (ty0 / 2 + py) * 24 + (tx0 / 2 + px)] = best;
    }
}

// ---------------- 7) convN (plane-per-block) + relu + pool via LDS ----------------
// block = COB * H * W threads
__global__ void convN_pool_kernel(const float* __restrict__ in, const float* __restrict__ w,
                                  const float* __restrict__ bias, float* __restrict__ out,
                                  int Cin, int H, int W, int COB,
                                  int pk, int ps, int PH, int PW)
{
    extern __shared__ float tile[];    // COB*H*W floats
    int hw = H * W;
    int col = threadIdx.x / hw;
    int pix = threadIdx.x % hw;
    int x = pix % W, y = pix / W;
    int co = blockIdx.x * COB + col;

    float acc = bias[co];
    const float* wco = w + (size_t)co * Cin * 9;
    for (int ci = 0; ci < Cin; ++ci) {
        const float* inp = in + (size_t)ci * hw;
        const float* wp = wco + ci * 9;
        #pragma unroll
        for (int ky = 0; ky < 3; ++ky) {
            int iy = y + ky - 1;
            if (iy < 0 || iy >= H) continue;
            #pragma unroll
            for (int kx = 0; kx < 3; ++kx) {
                int ix = x + kx - 1;
                if (ix < 0 || ix >= W) continue;
                acc += inp[iy * W + ix] * wp[ky * 3 + kx];
            }
        }
    }
    tile[threadIdx.x] = acc > 0.f ? acc : 0.f;
    __syncthreads();
    int npool = COB * PH * PW;
    if (threadIdx.x < npool) {
        int pcol = threadIdx.x / (PH * PW);
        int pp = threadIdx.x % (PH * PW);
        int py = pp / PW, px = pp % PW;
        float best = -INFINITY;
        for (int dy = 0; dy < pk; ++dy)
            for (int dx = 0; dx < pk; ++dx) {
                float v = tile[pcol * hw + (py * ps + dy) * W + (px * ps + dx)];
                best = v > best ? v : best;
            }
        out[((size_t)blockIdx.x * COB + pcol) * PH * PW + pp] = best;
    }
}

// ---------------- 8) head ----------------
__global__ void head_kernel(const float* __restrict__ feat,
                            const float* __restrict__ dnn_w, const float* __restrict__ dnn_b,
                            const float* __restrict__ out_w, const float* __restrict__ out_b,
                            float* __restrict__ out)
{
    __shared__ float y[128];
    __shared__ float logits[5];
    int j = threadIdx.x;
    float acc = dnn_b[j];
    for (int k = 0; k < 128; ++k) acc += feat[k] * dnn_w[j * 128 + k];
    y[j] = acc > 0.f ? acc : 0.f;
    __syncthreads();
    if (j < 5) {
        float a = out_b[j];
        for (int k = 0; k < 128; ++k) a += y[k] * out_w[j * 128 + k];
        logits[j] = a;
    }
    __syncthreads();
    if (j == 0) {
        float m = logits[0];
        for (int l = 1; l < 5; ++l) m = fmaxf(m, logits[l]);
        float s = 0.f;
        for (int l = 0; l < 5; ++l) s += expf(logits[l] - m);
        float lse = logf(s);
        for (int l = 0; l < 5; ++l) out[l] = logits[l] - m - lse;
    }
}

extern "C" void kernel_launch(void* const* d_in, const int* in_sizes, int n_in,
                              void* d_out, int out_size, void* d_ws, size_t ws_size,
                              hipStream_t stream)
{
    const int*   x1     = (const int*)d_in[0];
    const int*   x2     = (const int*)d_in[1];
    const float* emb    = (const float*)d_in[2];
    const float* w_ih_f = (const float*)d_in[3];
    const float* w_hh_f = (const float*)d_in[4];
    const float* b_f    = (const float*)d_in[5];
    const float* w_ih_b = (const float*)d_in[6];
    const float* w_hh_b = (const float*)d_in[7];
    const float* b_b    = (const float*)d_in[8];
    const float* c1_w   = (const float*)d_in[9];
    const float* c1_b   = (const float*)d_in[10];
    const float* c2_w   = (const float*)d_in[11];
    const float* c2_b   = (const float*)d_in[12];
    const float* c3_w   = (const float*)d_in[13];
    const float* c3_b   = (const float*)d_in[14];
    const float* c4_w   = (const float*)d_in[15];
    const float* c4_b   = (const float*)d_in[16];
    const float* c5_w   = (const float*)d_in[17];
    const float* c5_b   = (const float*)d_in[18];
    const float* dnn_w  = (const float*)d_in[19];
    const float* dnn_b  = (const float*)d_in[20];
    const float* out_w  = (const float*)d_in[21];
    const float* out_b  = (const float*)d_in[22];

    float* ws    = (float*)d_ws;
    float* xW    = ws + OFF_XW;
    float* hsb   = ws + OFF_HS;
    float* sc    = ws + OFF_SC;
    float* fc    = ws + OFF_FC;
    float* bufA  = ws + OFF_BUFA;
    float* bufB  = ws + OFF_BUFB;
    float* wihT  = ws + OFF_WIHT;
    float* hglob = ws + OFF_HGLOB;
    int*   cnt   = (int*)(ws + OFF_CNT);
    unsigned char* sel = (unsigned char*)(ws + OFF_SEL);
    float* outp  = (float*)d_out;

    transpose_wih_kernel<<<dim3(32, 10, 2), dim3(32, 32), 0, stream>>>(w_ih_f, w_ih_b, wihT, cnt);
    embed_xw_kernel<<<192, 512, 0, stream>>>(x1, x2, emb, wihT, xW);
    lstm_kernel<<<16, 256, 0, stream>>>(xW, w_hh_f, w_hh_b, b_f, b_b, hsb, hglob, cnt);
    sim_kernel<<<2304, 64, 0, stream>>>(hsb, sc);
    greedy_kernel<<<2, 64, 0, stream>>>(sc, sel);
    mask_kernel<<<(13 * 2304 + 255) / 256, 256, 0, stream>>>(sc, sel, fc);

    // conv stack: 13x48x48 ->128x24x24 ->164x12x12 ->192x6x6 ->192x3x3 ->128
    conv1_pool_kernel<<<128 * 9, 256, 0, stream>>>(fc, c1_w, c1_b, bufA);
    convN_pool_kernel<<<164, 576, 576 * 4, stream>>>(bufA, c2_w, c2_b, bufB, 128, 24, 24, 1, 2, 2, 12, 12);
    convN_pool_kernel<<<48, 576, 576 * 4, stream>>>(bufB, c3_w, c3_b, bufA, 164, 12, 12, 4, 2, 2, 6, 6);
    convN_pool_kernel<<<12, 576, 576 * 4, stream>>>(bufA, c4_w, c4_b, bufB, 192, 6, 6, 16, 2, 2, 3, 3);
    convN_pool_kernel<<<2, 576, 576 * 4, stream>>>(bufB, c5_w, c5_b, bufA, 192, 3, 3, 64, 3, 1, 1, 1);

    head_kernel<<<1, 128, 0, stream>>>(bufA, dnn_w, dnn_b, out_w, out_b, outp);
}

// Round 4
// 501.608 us; speedup vs baseline: 8.9857x; 2.0870x over previous
//
#include <hip/hip_runtime.h>
#include <math.h>

// ---------------- dims ----------------
// T=S=48, H=250, EMB=300, gates=1000, 13 sim planes, convnet 48->24->12->6->3->1

typedef __attribute__((ext_vector_type(2))) _Float16 h2f;

// workspace layout (floats)
#define OFF_XW    0            // 4*48*1000 = 192000
#define OFF_HS    192000       // 4*48*250  = 48000
#define OFF_SC    240000       // 13*2304 = 29952
#define OFF_BUFA  269952       // 73728 (conv1 out 128x24x24; conv3 out; conv5 out)
#define OFF_BUFB  343680       // 23616 (conv2 out 164x12x12; conv4 out)
#define OFF_WIHT  367296       // 600000 fp32 transposed w_ih [2][300][1000]
#define OFF_HGLOB 967296       // 1024 u32: [4 m][2 par][128] packed fp16 pairs
#define OFF_FLAGS 968320       // 256 ints: flag (m*4+s)*16
#define OFF_SEL   968576       // 2*2304 bytes = 1152 floats
// total ~969728 floats (~3.9 MB)

__device__ __forceinline__ float sigf(float x) { return 1.f / (1.f + expf(-x)); }

// ---------------- 0) tiled transpose w_ih + zero lstm flags ----------------
// grid dim3(32, 10, 2), block dim3(32, 32)
__global__ void transpose_wih_kernel(const float* __restrict__ wf, const float* __restrict__ wb,
                                     float* __restrict__ wT, int* __restrict__ flags)
{
    int tid = threadIdx.y * 32 + threadIdx.x;
    if (blockIdx.x == 0 && blockIdx.y == 0 && blockIdx.z == 0 && tid < 256)
        __hip_atomic_store(&flags[tid], 0, __ATOMIC_RELAXED, __HIP_MEMORY_SCOPE_AGENT);

    __shared__ float tile[32][33];
    int dir = blockIdx.z;
    const float* w = dir ? wb : wf;

    int j = blockIdx.x * 32 + threadIdx.y;   // row of w (0..999)
    int k = blockIdx.y * 32 + threadIdx.x;   // col of w (0..299)
    if (j < 1000 && k < 300)
        tile[threadIdx.y][threadIdx.x] = w[(size_t)j * 300 + k];
    __syncthreads();

    int ko = blockIdx.y * 32 + threadIdx.y;
    int jo = blockIdx.x * 32 + threadIdx.x;
    if (ko < 300 && jo < 1000)
        wT[(size_t)dir * 300000 + (size_t)ko * 1000 + jo] = tile[threadIdx.x][threadIdx.y];
}

// ---------------- 1) embedding gather + x @ w_ih^T (coalesced via wT) ----------------
__global__ void embed_xw_kernel(const int* __restrict__ x1, const int* __restrict__ x2,
                                const float* __restrict__ emb, const float* __restrict__ wT,
                                float* __restrict__ xW)
{
    int t = blockIdx.x % 48;
    int m = blockIdx.x / 48;
    const int* x = (m < 2) ? x1 : x2;
    const float* w = wT + (size_t)(m & 1) * 300000;

    __shared__ float e[300];
    int row = x[t];
    for (int k = threadIdx.x; k < 300; k += 512)
        e[k] = emb[(size_t)row * 300 + k];
    __syncthreads();

    int j0 = threadIdx.x;
    int j1 = threadIdx.x + 512;
    int j1c = j1 < 1000 ? j1 : 999;
    float a0 = 0.f, a1 = 0.f;
    #pragma unroll 4
    for (int k = 0; k < 300; ++k) {
        float ek = e[k];
        const float* wr = w + (size_t)k * 1000;
        a0 += ek * wr[j0];
        a1 += ek * wr[j1c];
    }
    float* out = xW + ((size_t)m * 48 + t) * 1000;
    out[j0] = a0;
    if (j1 < 1000) out[j1] = a1;
}

// ---------------- 2) LSTM: 16 blocks = 4 (seq,dir) x 4 row-slices ----------------
// h exchanged as packed fp16 pairs; per-block padded release flags; reg-resident fp16 weights.
__global__ void __launch_bounds__(256) lstm_kernel(
    const float* __restrict__ xW,
    const float* __restrict__ w_hh_f, const float* __restrict__ w_hh_b,
    const float* __restrict__ b_f, const float* __restrict__ b_b,
    float* __restrict__ hs, unsigned int* __restrict__ hglob, int* __restrict__ flags)
{
    int blk = blockIdx.x;
    int m   = blk >> 2;             // 0: s1 fwd, 1: s1 bwd, 2: s2 fwd, 3: s2 bwd
    int s   = blk & 3;              // row slice
    int dir = m & 1;
    const float* w    = dir ? w_hh_b : w_hh_f;
    const float* bias = dir ? b_b : b_f;
    const float* xw   = xW + (size_t)m * 48000;
    float* out        = hs + (size_t)m * 12000;

    const int NU   = (s == 0) ? 64 : 62;          // 64+62+62+62 = 250, all even
    const int base = (s == 0) ? 0 : 64 + (s - 1) * 62;
    const int ROWS = 4 * NU;

    int t = threadIdx.x;
    bool active = t < ROWS;
    int gate = t / NU; if (gate > 3) gate = 3;
    int u    = t - gate * NU;
    int grow = gate * 250 + base + u;

    __shared__ __align__(16) unsigned int hp[128];   // 250 fp16 h, packed pairs
    __shared__ float g_lds[256];

    // weights -> registers as packed fp16 pairs (125 VGPRs)
    h2f wreg[125];
    float bias_r = 0.f;
    if (active) {
        bias_r = bias[grow];
        const float* wr = w + (size_t)grow * 250;
        #pragma unroll
        for (int j = 0; j < 125; ++j) {
            float2 v = *(const float2*)(wr + 2 * j);
            h2f pv; pv.x = (_Float16)v.x; pv.y = (_Float16)v.y;
            wreg[j] = pv;
        }
    }
    if (t < 128) hp[t] = 0u;
    float c = 0.f;
    __syncthreads();

    unsigned int* hgl = hglob + (size_t)m * 256;   // [2 par][128]
    for (int step = 0; step < 48; ++step) {
        int tt  = dir ? 47 - step : step;
        int par = step & 1;
        if (active) {
            float acc = xw[tt * 1000 + grow] + bias_r;
            const uint4* hp4 = (const uint4*)hp;
            #pragma unroll
            for (int jj = 0; jj < 31; ++jj) {
                uint4 q = hp4[jj];
                h2f h0 = *(h2f*)&q.x, h1 = *(h2f*)&q.y, h2 = *(h2f*)&q.z, h3 = *(h2f*)&q.w;
                h2f w0 = wreg[4*jj], w1 = wreg[4*jj+1], w2 = wreg[4*jj+2], w3 = wreg[4*jj+3];
                acc += (float)h0.x * (float)w0.x + (float)h0.y * (float)w0.y;
                acc += (float)h1.x * (float)w1.x + (float)h1.y * (float)w1.y;
                acc += (float)h2.x * (float)w2.x + (float)h2.y * (float)w2.y;
                acc += (float)h3.x * (float)w3.x + (float)h3.y * (float)w3.y;
            }
            {
                unsigned int q = hp[124];
                h2f hv = *(h2f*)&q;
                h2f wv = wreg[124];
                acc += (float)hv.x * (float)wv.x + (float)hv.y * (float)wv.y;
            }
            g_lds[t] = acc;
        }
        __syncthreads();
        if (t < NU) {
            float iv = sigf(g_lds[t]);
            float fv = sigf(g_lds[NU + t]);
            float gv = tanhf(g_lds[2 * NU + t]);
            float ov = sigf(g_lds[3 * NU + t]);
            c = fv * c + iv * gv;
            float hn = ov * tanhf(c);
            out[tt * 250 + base + t] = hn;
            float hi = __shfl_down(hn, 1);
            if ((t & 1) == 0) {
                h2f pv; pv.x = (_Float16)hn; pv.y = (_Float16)hi;
                __hip_atomic_store(&hgl[par * 128 + (base >> 1) + (t >> 1)],
                                   *(unsigned int*)&pv, __ATOMIC_RELAXED, __HIP_MEMORY_SCOPE_AGENT);
            }
        }
        __syncthreads();   // drains h stores (vmcnt) before signaling
        if (t == 0)
            __hip_atomic_store(&flags[(m * 4 + s) * 16], step + 1,
                               __ATOMIC_RELEASE, __HIP_MEMORY_SCOPE_AGENT);
        if (t < 4) {
            const int fi = (m * 4 + t) * 16;
            while (__hip_atomic_load(&flags[fi], __ATOMIC_ACQUIRE, __HIP_MEMORY_SCOPE_AGENT)
                   < step + 1) {}
        }
        __syncthreads();
        if (t < 125)
            hp[t] = __hip_atomic_load(&hgl[par * 128 + t],
                                      __ATOMIC_RELAXED, __HIP_MEMORY_SCOPE_AGENT);
        __syncthreads();
    }
}

// ---------------- 3) similarity cube with inline norms: 13 x 48 x 48 ----------------
__global__ void sim_kernel(const float* __restrict__ hs, float* __restrict__ sc)
{
    int p = blockIdx.x;
    int i = p / 48, jj = p % 48;
    const float* h1f = hs + ((size_t)0 * 48 + i) * 250;
    const float* h1b = hs + ((size_t)1 * 48 + i) * 250;
    const float* h2f = hs + ((size_t)2 * 48 + jj) * 250;
    const float* h2b = hs + ((size_t)3 * 48 + jj) * 250;
    int lane = threadIdx.x;
    float dff = 0.f, dbb = 0.f, dfb = 0.f, dbf = 0.f;
    float sfa = 0.f, sba = 0.f, caa = 0.f;
    float sfb = 0.f, sbb = 0.f, cbb = 0.f;
    for (int k = lane; k < 250; k += 64) {
        float af = h1f[k], ab = h1b[k], bf = h2f[k], bb = h2b[k];
        dff += af * bf; dbb += ab * bb; dfb += af * bb; dbf += ab * bf;
        sfa += af * af; sba += ab * ab; caa += af * ab;
        sfb += bf * bf; sbb += bb * bb; cbb += bf * bb;
    }
    #pragma unroll
    for (int o = 32; o; o >>= 1) {
        dff += __shfl_down(dff, o); dbb += __shfl_down(dbb, o);
        dfb += __shfl_down(dfb, o); dbf += __shfl_down(dbf, o);
        sfa += __shfl_down(sfa, o); sba += __shfl_down(sba, o);
        caa += __shfl_down(caa, o);
        sfb += __shfl_down(sfb, o); sbb += __shfl_down(sbb, o);
        cbb += __shfl_down(cbb, o);
    }
    if (lane == 0) {
        #define EMIT(basep, dotv, sa2, sb2)                                 \
        {                                                                   \
            float na = sqrtf(sa2), nbv = sqrtf(sb2);                        \
            float dv = (dotv);                                              \
            sc[(basep) * 2304 + p] = dv;                                    \
            sc[((basep) + 1) * 2304 + p] = dv / (na * nbv + 1e-8f);         \
            float d2 = fmaxf(na * na + nbv * nbv - 2.f * dv, 1e-12f);       \
            sc[((basep) + 2) * 2304 + p] = sqrtf(d2);                       \
        }
        EMIT(0, dff + dbb, sfa + sba, sfb + sbb);
        EMIT(3, dff, sfa, sfb);
        EMIT(6, dbb, sba, sbb);
        EMIT(9, dff + dfb + dbf + dbb, sfa + sba + 2.f * caa, sfb + sbb + 2.f * cbb);
        #undef EMIT
        // plane 12 is identically zero and skipped by conv1
    }
}

// ---------------- 4) greedy top-k: 2 blocks (one per plane), single wave each ----------------
__global__ void greedy_kernel(const float* __restrict__ sc, unsigned char* __restrict__ sel)
{
    __shared__ float vals[2304];
    __shared__ int s1[48], s2[48];
    __shared__ unsigned char selL[2304];
    int lane = threadIdx.x;
    int plane = 10 + blockIdx.x;

    for (int q = 0; q < 36; ++q) {
        int i = lane + 64 * q;
        vals[i] = sc[plane * 2304 + i];
        selL[i] = 0;
    }
    if (lane < 48) { s1[lane] = 0; s2[lane] = 0; }
    __syncthreads();

    float lv = -INFINITY; int li = 0x7fffffff;
    for (int q = 0; q < 36; ++q) {
        int i = lane + 64 * q;
        float v = vals[i];
        if (v > lv) { lv = v; li = i; }
    }

    for (int it = 0; it < 96; ++it) {
        float bv = lv; int bi = li;
        #pragma unroll
        for (int o = 1; o < 64; o <<= 1) {
            float ov = __shfl_xor(bv, o);
            int   oi = __shfl_xor(bi, o);
            if (ov > bv || (ov == bv && oi < bi)) { bv = ov; bi = oi; }
        }
        if (lane == (bi & 63)) {
            vals[bi] = -INFINITY;
            lv = -INFINITY; li = 0x7fffffff;
            for (int q = 0; q < 36; ++q) {
                int i = lane + 64 * q;
                float v = vals[i];
                if (v > lv) { lv = v; li = i; }
            }
        }
        if (lane == 0) {
            int p1 = bi / 48, p2 = bi % 48;
            if (s1[p1] + s2[p2] == 0) { s1[p1] = 1; s2[p2] = 1; selL[bi] = 1; }
        }
    }
    __syncthreads();
    for (int q = 0; q < 36; ++q) {
        int i = lane + 64 * q;
        sel[blockIdx.x * 2304 + i] = selL[i];
    }
}

// ---------------- 5) conv1 (12 planes ->128, 48x48) + fused focus mask + relu + pool2x2 ----------------
// grid 128*9, block 256 (16x16 tile)
__global__ void conv1_pool_kernel(const float* __restrict__ sc, const unsigned char* __restrict__ sel,
                                  const float* __restrict__ w, const float* __restrict__ bias,
                                  float* __restrict__ out)
{
    __shared__ float tile[256];
    int co  = blockIdx.x / 9;
    int tl  = blockIdx.x % 9;
    int ty0 = (tl / 3) * 16, tx0 = (tl % 3) * 16;
    int tx = threadIdx.x % 16, ty = threadIdx.x / 16;
    int x = tx0 + tx, y = ty0 + ty;

    // 9 neighborhood masks (mask depends only on pixel, not channel)
    float mv[9];
    #pragma unroll
    for (int ky = 0; ky < 3; ++ky) {
        int iy = y + ky - 1;
        #pragma unroll
        for (int kx = 0; kx < 3; ++kx) {
            int ix = x + kx - 1;
            float mm = 0.f;
            if (iy >= 0 && iy < 48 && ix >= 0 && ix < 48) {
                int p = iy * 48 + ix;
                mm = (sel[p] | sel[2304 + p]) ? 1.0f : 0.1f;
            }
            mv[ky * 3 + kx] = mm;     // 0 outside = skip
        }
    }

    float acc = bias[co];
    const float* wco = w + (size_t)co * 13 * 9;
    for (int ci = 0; ci < 12; ++ci) {     // plane 12 is zero -> skip
        const float* inp = sc + (size_t)ci * 2304;
        const float* wp = wco + ci * 9;
        #pragma unroll
        for (int ky = 0; ky < 3; ++ky) {
            int iy = y + ky - 1;
            if (iy < 0 || iy >= 48) continue;
            #pragma unroll
            for (int kx = 0; kx < 3; ++kx) {
                int ix = x + kx - 1;
                if (ix < 0 || ix >= 48) continue;
                acc += inp[iy * 48 + ix] * mv[ky * 3 + kx] * wp[ky * 3 + kx];
            }
        }
    }
    tile[threadIdx.x] = acc > 0.f ? acc : 0.f;
    __syncthreads();
    if (threadIdx.x < 64) {
        int py = threadIdx.x / 8, px = threadIdx.x % 8;
        float a = tile[(py * 2) * 16 + px * 2];
        float b = tile[(py * 2) * 16 + px * 2 + 1];
        float cc = tile[(py * 2 + 1) * 16 + px * 2];
        float d = tile[(py * 2 + 1) * 16 + px * 2 + 1];
        float best = fmaxf(fmaxf(a, b), fmaxf(cc, d));
        out[(size_t)co * 576 + (ty0 / 2 + py) * 24 + (tx0 / 2 + px)] = best;
    }
}

// ---------------- 6) Cin-split conv3x3 + relu + pool ----------------
// grid (Cout, tilesY, tilesX); block = P*CC threads, P = tileH*tileW
__global__ void conv_cs_kernel(const float* __restrict__ in, const float* __restrict__ w,
                               const float* __restrict__ bias, float* __restrict__ out,
                               int Cin, int H, int W, int tileH, int tileW,
                               int cpc, int CC, int pk, int ps, int PHf, int PWf)
{
    extern __shared__ float sm[];          // P*CC partials + P results
    int P = tileH * tileW;
    int co = blockIdx.x;
    int ty0 = blockIdx.y * tileH, tx0 = blockIdx.z * tileW;
    int t = threadIdx.x;
    int pix = t % P, chunk = t / P;
    int y = ty0 + pix / tileW, x = tx0 + pix % tileW;
    int c0 = chunk * cpc;
    int c1 = c0 + cpc; if (c1 > Cin) c1 = Cin;

    float acc = 0.f;
    const float* wco = w + (size_t)co * Cin * 9;
    for (int ci = c0; ci < c1; ++ci) {
        const float* inp = in + (size_t)ci * H * W;
        const float* wp = wco + (size_t)ci * 9;
        #pragma unroll
        for (int ky = 0; ky < 3; ++ky) {
            int iy = y + ky - 1;
            if (iy < 0 || iy >= H) continue;
            const float* rowp = inp + iy * W;
            #pragma unroll
            for (int kx = 0; kx < 3; ++kx) {
                int ix = x + kx - 1;
                if (ix < 0 || ix >= W) continue;
                acc += rowp[ix] * wp[ky * 3 + kx];
            }
        }
    }
    sm[t] = acc;
    __syncthreads();
    float* res = sm + P * CC;
    if (chunk == 0) {
        float tot = bias[co];
        for (int cc2 = 0; cc2 < CC; ++cc2) tot += sm[pix + cc2 * P];
        res[pix] = tot > 0.f ? tot : 0.f;
    }
    __syncthreads();
    int pH = (tileH - pk) / ps + 1, pW = (tileW - pk) / ps + 1;
    if (t < pH * pW) {
        int py = t / pW, px = t % pW;
        float best = -INFINITY;
        for (int dy = 0; dy < pk; ++dy)
            for (int dx = 0; dx < pk; ++dx) {
                float v = res[(py * ps + dy) * tileW + (px * ps + dx)];
                best = v > best ? v : best;
            }
        out[((size_t)co * PHf + (ty0 / ps + py)) * PWf + (tx0 / ps + px)] = best;
    }
}

// ---------------- 7) head ----------------
__global__ void head_kernel(const float* __restrict__ feat,
                            const float* __restrict__ dnn_w, const float* __restrict__ dnn_b,
                            const float* __restrict__ out_w, const float* __restrict__ out_b,
                            float* __restrict__ out)
{
    __shared__ float y[128];
    __shared__ float logits[5];
    int j = threadIdx.x;
    float acc = dnn_b[j];
    for (int k = 0; k < 128; ++k) acc += feat[k] * dnn_w[j * 128 + k];
    y[j] = acc > 0.f ? acc : 0.f;
    __syncthreads();
    if (j < 5) {
        float a = out_b[j];
        for (int k = 0; k < 128; ++k) a += y[k] * out_w[j * 128 + k];
        logits[j] = a;
    }
    __syncthreads();
    if (j == 0) {
        float m = logits[0];
        for (int l = 1; l < 5; ++l) m = fmaxf(m, logits[l]);
        float s = 0.f;
        for (int l = 0; l < 5; ++l) s += expf(logits[l] - m);
        float lse = logf(s);
        for (int l = 0; l < 5; ++l) out[l] = logits[l] - m - lse;
    }
}

extern "C" void kernel_launch(void* const* d_in, const int* in_sizes, int n_in,
                              void* d_out, int out_size, void* d_ws, size_t ws_size,
                              hipStream_t stream)
{
    const int*   x1     = (const int*)d_in[0];
    const int*   x2     = (const int*)d_in[1];
    const float* emb    = (const float*)d_in[2];
    const float* w_ih_f = (const float*)d_in[3];
    const float* w_hh_f = (const float*)d_in[4];
    const float* b_f    = (const float*)d_in[5];
    const float* w_ih_b = (const float*)d_in[6];
    const float* w_hh_b = (const float*)d_in[7];
    const float* b_b    = (const float*)d_in[8];
    const float* c1_w   = (const float*)d_in[9];
    const float* c1_b   = (const float*)d_in[10];
    const float* c2_w   = (const float*)d_in[11];
    const float* c2_b   = (const float*)d_in[12];
    const float* c3_w   = (const float*)d_in[13];
    const float* c3_b   = (const float*)d_in[14];
    const float* c4_w   = (const float*)d_in[15];
    const float* c4_b   = (const float*)d_in[16];
    const float* c5_w   = (const float*)d_in[17];
    const float* c5_b   = (const float*)d_in[18];
    const float* dnn_w  = (const float*)d_in[19];
    const float* dnn_b  = (const float*)d_in[20];
    const float* out_w  = (const float*)d_in[21];
    const float* out_b  = (const float*)d_in[22];

    float* ws    = (float*)d_ws;
    float* xW    = ws + OFF_XW;
    float* hsb   = ws + OFF_HS;
    float* sc    = ws + OFF_SC;
    float* bufA  = ws + OFF_BUFA;
    float* bufB  = ws + OFF_BUFB;
    float* wihT  = ws + OFF_WIHT;
    unsigned int* hglob = (unsigned int*)(ws + OFF_HGLOB);
    int*   flags = (int*)(ws + OFF_FLAGS);
    unsigned char* sel = (unsigned char*)(ws + OFF_SEL);
    float* outp  = (float*)d_out;

    transpose_wih_kernel<<<dim3(32, 10, 2), dim3(32, 32), 0, stream>>>(w_ih_f, w_ih_b, wihT, flags);
    embed_xw_kernel<<<192, 512, 0, stream>>>(x1, x2, emb, wihT, xW);
    lstm_kernel<<<16, 256, 0, stream>>>(xW, w_hh_f, w_hh_b, b_f, b_b, hsb, hglob, flags);
    sim_kernel<<<2304, 64, 0, stream>>>(hsb, sc);
    greedy_kernel<<<2, 64, 0, stream>>>(sc, sel);

    // conv stack: 13x48x48 ->128x24x24 ->164x12x12 ->192x6x6 ->192x3x3 ->128
    conv1_pool_kernel<<<128 * 9, 256, 0, stream>>>(sc, sel, c1_w, c1_b, bufA);
    conv_cs_kernel<<<dim3(164, 2, 2), 576, (576 + 144) * 4, stream>>>(
        bufA, c2_w, c2_b, bufB, 128, 24, 24, 12, 12, 32, 4, 2, 2, 12, 12);
    conv_cs_kernel<<<dim3(192, 1, 1), 576, (576 + 144) * 4, stream>>>(
        bufB, c3_w, c3_b, bufA, 164, 12, 12, 12, 12, 41, 4, 2, 2, 6, 6);
    conv_cs_kernel<<<dim3(192, 1, 1), 576, (576 + 36) * 4, stream>>>(
        bufA, c4_w, c4_b, bufB, 192, 6, 6, 6, 6, 12, 16, 2, 2, 3, 3);
    conv_cs_kernel<<<dim3(128, 1, 1), 576, (576 + 9) * 4, stream>>>(
        bufB, c5_w, c5_b, bufA, 192, 3, 3, 3, 3, 3, 64, 3, 1, 1, 1);

    head_kernel<<<1, 128, 0, stream>>>(bufA, dnn_w, dnn_b, out_w, out_b, outp);
}